// Round 1
// baseline (953.105 us; speedup 1.0000x reference)
//
#include <hip/hip_runtime.h>
#include <hip/hip_bf16.h>
#include <math.h>
#include <stdint.h>

#define DIM 1024
#define FF 4096
#define NE 8
#define NTOK 8192
#define NASSIGN (NTOK * 2)

typedef short short8 __attribute__((ext_vector_type(8)));
typedef float f32x4 __attribute__((ext_vector_type(4)));

static __device__ __forceinline__ short bf16_of(float f) {
    union { float f; unsigned u; } v; v.f = f;
    unsigned r = v.u + 0x7fffu + ((v.u >> 16) & 1u);   // RNE
    return (short)(r >> 16);
}

static __device__ __forceinline__ short8 cvt8(float4 a, float4 b) {
    short8 r;
    r[0] = bf16_of(a.x); r[1] = bf16_of(a.y); r[2] = bf16_of(a.z); r[3] = bf16_of(a.w);
    r[4] = bf16_of(b.x); r[5] = bf16_of(b.y); r[6] = bf16_of(b.z); r[7] = bf16_of(b.w);
    return r;
}

// ---------------- router ----------------
__global__ void router_k(const float* __restrict__ x, const float* __restrict__ Wr,
                         int* __restrict__ cnt, int* __restrict__ a_exp,
                         int* __restrict__ a_pos, float* __restrict__ a_w) {
    int t = blockIdx.x;
    int lane = threadIdx.x;
    const float* xr = x + (size_t)t * DIM;
    float p[NE];
#pragma unroll
    for (int e = 0; e < NE; ++e) p[e] = 0.f;
    for (int i = 0; i < DIM / 64; ++i) {
        float xv = xr[lane + i * 64];
#pragma unroll
        for (int e = 0; e < NE; ++e) p[e] += xv * Wr[e * DIM + lane + i * 64];
    }
#pragma unroll
    for (int off = 32; off >= 1; off >>= 1)
#pragma unroll
        for (int e = 0; e < NE; ++e) p[e] += __shfl_xor(p[e], off);
    if (lane == 0) {
        float mx = p[0];
#pragma unroll
        for (int e = 1; e < NE; ++e) mx = fmaxf(mx, p[e]);
        float pr[NE]; float s = 0.f;
#pragma unroll
        for (int e = 0; e < NE; ++e) { pr[e] = expf(p[e] - mx); s += pr[e]; }
#pragma unroll
        for (int e = 0; e < NE; ++e) pr[e] /= s;
        int i1 = 0;
#pragma unroll
        for (int e = 1; e < NE; ++e) if (pr[e] > pr[i1]) i1 = e;
        int i2 = (i1 == 0) ? 1 : 0;
#pragma unroll
        for (int e = 0; e < NE; ++e) if (e != i1 && pr[e] > pr[i2]) i2 = e;
        float w1 = pr[i1], w2 = pr[i2], nrm = w1 + w2;
        w1 /= nrm; w2 /= nrm;
        int p1 = atomicAdd(&cnt[i1], 1);
        int p2 = atomicAdd(&cnt[i2], 1);
        a_exp[2 * t] = i1;     a_pos[2 * t] = p1;     a_w[2 * t] = w1;
        a_exp[2 * t + 1] = i2; a_pos[2 * t + 1] = p2; a_w[2 * t + 1] = w2;
    }
}

__global__ void offsets_k(const int* __restrict__ cnt, int* __restrict__ offs) {
    if (threadIdx.x == 0) {
        int s = 0;
        for (int e = 0; e < NE; ++e) { offs[e] = s; s += cnt[e]; }
        offs[NE] = s;
    }
}

__global__ void scatter_k(const int* __restrict__ a_exp, const int* __restrict__ a_pos,
                          const float* __restrict__ a_w, const int* __restrict__ offs,
                          int* __restrict__ ptok, float* __restrict__ pw) {
    int a = blockIdx.x * blockDim.x + threadIdx.x;
    if (a >= NASSIGN) return;
    int e = a_exp[a];
    int r = offs[e] + a_pos[a];
    ptok[r] = a >> 1;
    pw[r] = a_w[a];
}

// ---------------- grouped GEMM core ----------------
// C[128x128] = A[128 x KDIM] * B[128 x KDIM]^T  (both K-contiguous), bf16 MFMA.
// A rows gathered (A_IS_F32: token rows of x, f32) or direct (H, bf16).
template <int KDIM, bool A_IS_F32>
__device__ __forceinline__ void gemm_tile(const void* __restrict__ Asrc,
                                          const int* __restrict__ ptok,
                                          const float* __restrict__ Bsrc,
                                          int offs_e, int cnt_e, int m0, int n0,
                                          f32x4 acc[4][4]) {
    __shared__ __align__(16) short As[128 * 32];
    __shared__ __align__(16) short Bs[128 * 32];

    int tid = threadIdx.x;
    int lane = tid & 63, wave = tid >> 6;
    int wr = wave >> 1, wc = wave & 1;

#pragma unroll
    for (int i = 0; i < 4; ++i)
#pragma unroll
        for (int j = 0; j < 4; ++j) acc[i][j] = (f32x4){0.f, 0.f, 0.f, 0.f};

    // staging chunks: chunk c (0..511) -> row c>>2, kq c&3 (8 bf16 = 16B per chunk)
    const int c0 = tid, c1 = tid + 256;
    const int ar0 = c0 >> 2, kq0 = c0 & 3;
    const int ar1 = c1 >> 2, kq1 = c1 & 3;

    size_t arow0, arow1;
    if (A_IS_F32) {
        int gm0 = min(m0 + ar0, cnt_e - 1);
        int gm1 = min(m0 + ar1, cnt_e - 1);
        arow0 = (size_t)ptok[offs_e + gm0] * KDIM;
        arow1 = (size_t)ptok[offs_e + gm1] * KDIM;
    } else {
        int gm0 = min(m0 + ar0, cnt_e - 1);
        int gm1 = min(m0 + ar1, cnt_e - 1);
        arow0 = (size_t)(offs_e + gm0) * KDIM;
        arow1 = (size_t)(offs_e + gm1) * KDIM;
    }
    const size_t brow0 = (size_t)(n0 + ar0) * KDIM;
    const size_t brow1 = (size_t)(n0 + ar1) * KDIM;

    const int fr = lane & 15, kg = (lane >> 4) * 8;

    for (int kt = 0; kt < KDIM / 32; ++kt) {
        const int k0 = kt * 32;
        short8 aV0, aV1, bV0, bV1;
        if (A_IS_F32) {
            const float* a0 = (const float*)Asrc + arow0 + k0 + kq0 * 8;
            const float* a1 = (const float*)Asrc + arow1 + k0 + kq1 * 8;
            aV0 = cvt8(*(const float4*)a0, *(const float4*)(a0 + 4));
            aV1 = cvt8(*(const float4*)a1, *(const float4*)(a1 + 4));
        } else {
            const short* a0 = (const short*)Asrc + arow0 + k0 + kq0 * 8;
            const short* a1 = (const short*)Asrc + arow1 + k0 + kq1 * 8;
            aV0 = *(const short8*)a0;
            aV1 = *(const short8*)a1;
        }
        {
            const float* b0 = Bsrc + brow0 + k0 + kq0 * 8;
            const float* b1p = Bsrc + brow1 + k0 + kq1 * 8;
            bV0 = cvt8(*(const float4*)b0, *(const float4*)(b0 + 4));
            bV1 = cvt8(*(const float4*)b1p, *(const float4*)(b1p + 4));
        }
        __syncthreads();   // previous iter's LDS reads complete
        *(short8*)&As[ar0 * 32 + kq0 * 8] = aV0;
        *(short8*)&As[ar1 * 32 + kq1 * 8] = aV1;
        *(short8*)&Bs[ar0 * 32 + kq0 * 8] = bV0;
        *(short8*)&Bs[ar1 * 32 + kq1 * 8] = bV1;
        __syncthreads();   // writes visible

        short8 af[4], bf[4];
#pragma unroll
        for (int i = 0; i < 4; ++i) af[i] = *(short8*)&As[(wr * 64 + i * 16 + fr) * 32 + kg];
#pragma unroll
        for (int j = 0; j < 4; ++j) bf[j] = *(short8*)&Bs[(wc * 64 + j * 16 + fr) * 32 + kg];
#pragma unroll
        for (int i = 0; i < 4; ++i)
#pragma unroll
            for (int j = 0; j < 4; ++j)
                acc[i][j] = __builtin_amdgcn_mfma_f32_16x16x32_bf16(af[i], bf[j], acc[i][j], 0, 0, 0);
    }
}

// ---------------- GEMM1: H = gelu(Xg @ W1[e]^T + b1[e]) ----------------
__global__ __launch_bounds__(256) void gemm1_k(const float* __restrict__ x,
                                               const float* __restrict__ W1,
                                               const float* __restrict__ b1,
                                               const int* __restrict__ cnt,
                                               const int* __restrict__ offs,
                                               const int* __restrict__ ptok,
                                               short* __restrict__ H) {
    const int e = blockIdx.z;
    const int cnt_e = cnt[e], offs_e = offs[e];
    const int m0 = blockIdx.y * 128;
    if (m0 >= cnt_e) return;
    const int n0 = blockIdx.x * 128;

    f32x4 acc[4][4];
    gemm_tile<DIM, true>(x, ptok, W1 + (size_t)e * FF * DIM, offs_e, cnt_e, m0, n0, acc);

    const int lane = threadIdx.x & 63, wave = threadIdx.x >> 6;
    const int wr = wave >> 1, wc = wave & 1;
    const int colb = lane & 15, rowb = (lane >> 4) * 4;
#pragma unroll
    for (int i = 0; i < 4; ++i) {
#pragma unroll
        for (int r = 0; r < 4; ++r) {
            const int gm = m0 + wr * 64 + i * 16 + rowb + r;
            if (gm >= cnt_e) continue;
#pragma unroll
            for (int j = 0; j < 4; ++j) {
                const int n = n0 + wc * 64 + j * 16 + colb;
                float v = acc[i][j][r] + b1[e * FF + n];
                v = 0.5f * v * (1.f + erff(v * 0.70710678118f));
                H[(size_t)(offs_e + gm) * FF + n] = bf16_of(v);
            }
        }
    }
}

// ---------------- GEMM2: out += gate * (H @ W2[e]^T + b2[e]) ----------------
__global__ __launch_bounds__(256) void gemm2_k(const short* __restrict__ H,
                                               const float* __restrict__ W2,
                                               const float* __restrict__ b2,
                                               const int* __restrict__ cnt,
                                               const int* __restrict__ offs,
                                               const int* __restrict__ ptok,
                                               const float* __restrict__ pw,
                                               float* __restrict__ out) {
    const int e = blockIdx.z;
    const int cnt_e = cnt[e], offs_e = offs[e];
    const int m0 = blockIdx.y * 128;
    if (m0 >= cnt_e) return;
    const int n0 = blockIdx.x * 128;

    f32x4 acc[4][4];
    gemm_tile<FF, false>(H, nullptr, W2 + (size_t)e * DIM * FF, offs_e, cnt_e, m0, n0, acc);

    const int lane = threadIdx.x & 63, wave = threadIdx.x >> 6;
    const int wr = wave >> 1, wc = wave & 1;
    const int colb = lane & 15, rowb = (lane >> 4) * 4;
#pragma unroll
    for (int i = 0; i < 4; ++i) {
#pragma unroll
        for (int r = 0; r < 4; ++r) {
            const int gm = m0 + wr * 64 + i * 16 + rowb + r;
            if (gm >= cnt_e) continue;
            const int tok = ptok[offs_e + gm];
            const float g = pw[offs_e + gm];
#pragma unroll
            for (int j = 0; j < 4; ++j) {
                const int n = n0 + wc * 64 + j * 16 + colb;
                float v = acc[i][j][r] + b2[e * DIM + n];
                atomicAdd(&out[(size_t)tok * DIM + n], g * v);
            }
        }
    }
}

// ---------------- launch ----------------
extern "C" void kernel_launch(void* const* d_in, const int* in_sizes, int n_in,
                              void* d_out, int out_size, void* d_ws, size_t ws_size,
                              hipStream_t stream) {
    const float* x  = (const float*)d_in[0];
    const float* Wr = (const float*)d_in[1];
    const float* W1 = (const float*)d_in[2];
    const float* b1 = (const float*)d_in[3];
    const float* W2 = (const float*)d_in[4];
    const float* b2 = (const float*)d_in[5];
    float* out = (float*)d_out;

    char* w = (char*)d_ws;
    int*   cnt   = (int*)w;                           // 8 ints
    int*   offs  = (int*)(w + 64);                    // 9 ints
    int*   a_exp = (int*)(w + 128);
    int*   a_pos = a_exp + NASSIGN;
    int*   ptok  = a_pos + NASSIGN;
    float* a_w   = (float*)(ptok + NASSIGN);
    float* pw    = a_w + NASSIGN;
    short* H     = (short*)(((uintptr_t)(pw + NASSIGN) + 255) & ~(uintptr_t)255);

    hipMemsetAsync(cnt, 0, 32, stream);
    hipMemsetAsync(out, 0, (size_t)NTOK * DIM * sizeof(float), stream);

    router_k<<<NTOK, 64, 0, stream>>>(x, Wr, cnt, a_exp, a_pos, a_w);
    offsets_k<<<1, 64, 0, stream>>>(cnt, offs);
    scatter_k<<<NASSIGN / 256, 256, 0, stream>>>(a_exp, a_pos, a_w, offs, ptok, pw);

    gemm1_k<<<dim3(FF / 128, NTOK / 128, NE), 256, 0, stream>>>(x, W1, b1, cnt, offs, ptok, H);
    gemm2_k<<<dim3(DIM / 128, NTOK / 128, NE), 256, 0, stream>>>(H, W2, b2, cnt, offs, ptok, pw, out);
}

// Round 2
// 836.361 us; speedup vs baseline: 1.1396x; 1.1396x over previous
//
#include <hip/hip_runtime.h>
#include <hip/hip_bf16.h>
#include <math.h>
#include <stdint.h>

#define DIM 1024
#define FF 4096
#define NE 8
#define NTOK 8192
#define NASSIGN (NTOK * 2)

typedef short short8 __attribute__((ext_vector_type(8)));
typedef float f32x4 __attribute__((ext_vector_type(4)));

static __device__ __forceinline__ short bf16_of(float f) {
    union { float f; unsigned u; } v; v.f = f;
    unsigned r = v.u + 0x7fffu + ((v.u >> 16) & 1u);   // RNE
    return (short)(r >> 16);
}

static __device__ __forceinline__ short8 cvt8(float4 a, float4 b) {
    short8 r;
    r[0] = bf16_of(a.x); r[1] = bf16_of(a.y); r[2] = bf16_of(a.z); r[3] = bf16_of(a.w);
    r[4] = bf16_of(b.x); r[5] = bf16_of(b.y); r[6] = bf16_of(b.z); r[7] = bf16_of(b.w);
    return r;
}

static __device__ __forceinline__ void gl_lds16(const short* g, short* lds) {
    __builtin_amdgcn_global_load_lds(
        (const __attribute__((address_space(1))) void*)g,
        (__attribute__((address_space(3))) void*)lds, 16, 0, 0);
}

// ---------------- f32 -> bf16 bulk convert ----------------
__global__ __launch_bounds__(256) void cvt_k(const float* __restrict__ in,
                                             short* __restrict__ out, int n8) {
    int i = blockIdx.x * blockDim.x + threadIdx.x;
    if (i >= n8) return;
    float4 a = ((const float4*)in)[2 * i];
    float4 b = ((const float4*)in)[2 * i + 1];
    ((short8*)out)[i] = cvt8(a, b);
}

// ---------------- router ----------------
__global__ void router_k(const float* __restrict__ x, const float* __restrict__ Wr,
                         int* __restrict__ cnt, int* __restrict__ a_exp,
                         int* __restrict__ a_pos, float* __restrict__ a_w) {
    int t = blockIdx.x;
    int lane = threadIdx.x;
    const float* xr = x + (size_t)t * DIM;
    float p[NE];
#pragma unroll
    for (int e = 0; e < NE; ++e) p[e] = 0.f;
    for (int i = 0; i < DIM / 64; ++i) {
        float xv = xr[lane + i * 64];
#pragma unroll
        for (int e = 0; e < NE; ++e) p[e] += xv * Wr[e * DIM + lane + i * 64];
    }
#pragma unroll
    for (int off = 32; off >= 1; off >>= 1)
#pragma unroll
        for (int e = 0; e < NE; ++e) p[e] += __shfl_xor(p[e], off);
    if (lane == 0) {
        float mx = p[0];
#pragma unroll
        for (int e = 1; e < NE; ++e) mx = fmaxf(mx, p[e]);
        float pr[NE]; float s = 0.f;
#pragma unroll
        for (int e = 0; e < NE; ++e) { pr[e] = expf(p[e] - mx); s += pr[e]; }
#pragma unroll
        for (int e = 0; e < NE; ++e) pr[e] /= s;
        int i1 = 0;
#pragma unroll
        for (int e = 1; e < NE; ++e) if (pr[e] > pr[i1]) i1 = e;
        int i2 = (i1 == 0) ? 1 : 0;
#pragma unroll
        for (int e = 0; e < NE; ++e) if (e != i1 && pr[e] > pr[i2]) i2 = e;
        float w1 = pr[i1], w2 = pr[i2], nrm = w1 + w2;
        w1 /= nrm; w2 /= nrm;
        int p1 = atomicAdd(&cnt[i1], 1);
        int p2 = atomicAdd(&cnt[i2], 1);
        a_exp[2 * t] = i1;     a_pos[2 * t] = p1;     a_w[2 * t] = w1;
        a_exp[2 * t + 1] = i2; a_pos[2 * t + 1] = p2; a_w[2 * t + 1] = w2;
    }
}

__global__ void offsets_k(const int* __restrict__ cnt, int* __restrict__ offs) {
    if (threadIdx.x == 0) {
        int s = 0;
        for (int e = 0; e < NE; ++e) { offs[e] = s; s += cnt[e]; }
        offs[NE] = s;
    }
}

__global__ void scatter_k(const int* __restrict__ a_exp, const int* __restrict__ a_pos,
                          const float* __restrict__ a_w, const int* __restrict__ offs,
                          int* __restrict__ ptok, float* __restrict__ pw) {
    int a = blockIdx.x * blockDim.x + threadIdx.x;
    if (a >= NASSIGN) return;
    int e = a_exp[a];
    int r = offs[e] + a_pos[a];
    ptok[r] = a >> 1;
    pw[r] = a_w[a];
}

// ---------------- grouped GEMM core (bf16, global_load_lds staging) ----------------
// C[128x128] = A[128 x KDIM] * B[128 x KDIM]^T, both bf16, K-contiguous rows.
// A rows gathered through ptok (GATHER) or contiguous at offs_e.
template <int KDIM, bool GATHER>
__device__ __forceinline__ void gemm_core(const short* __restrict__ A,
                                          const int* __restrict__ ptok,
                                          const short* __restrict__ B,
                                          int offs_e, int cnt_e, int m0, int n0,
                                          f32x4 acc[4][4],
                                          short* As, short* Bs) {
    const int tid = threadIdx.x;
    const int lane = tid & 63, wave = tid >> 6;
    const int wr = wave >> 1, wc = wave & 1;

#pragma unroll
    for (int i = 0; i < 4; ++i)
#pragma unroll
        for (int j = 0; j < 4; ++j) acc[i][j] = (f32x4){0.f, 0.f, 0.f, 0.f};

    // chunk c = tid (+256): row = c>>2 (chunk tid+256 -> row+64, same kq)
    const int ar = tid >> 2, kq = tid & 3;

    int gm0 = m0 + ar;      if (gm0 >= cnt_e) gm0 = cnt_e - 1;
    int gm1 = m0 + ar + 64; if (gm1 >= cnt_e) gm1 = cnt_e - 1;
    const short* arow0 = A + (GATHER ? (size_t)ptok[offs_e + gm0]
                                     : (size_t)(offs_e + gm0)) * KDIM + kq * 8;
    const short* arow1 = A + (GATHER ? (size_t)ptok[offs_e + gm1]
                                     : (size_t)(offs_e + gm1)) * KDIM + kq * 8;
    const short* brow0 = B + (size_t)(n0 + ar) * KDIM + kq * 8;
    const short* brow1 = B + (size_t)(n0 + ar + 64) * KDIM + kq * 8;

    short* ldsA0 = As + tid * 8;
    short* ldsA1 = As + (tid + 256) * 8;
    short* ldsB0 = Bs + tid * 8;
    short* ldsB1 = Bs + (tid + 256) * 8;

    const int fr = lane & 15, kg = (lane >> 4) * 8;

    // prologue: stage kt=0
    gl_lds16(arow0, ldsA0); gl_lds16(arow1, ldsA1);
    gl_lds16(brow0, ldsB0); gl_lds16(brow1, ldsB1);

    for (int kt = 0; kt < KDIM / 32; ++kt) {
        __syncthreads();   // barrier drains vmcnt -> tile kt resident in LDS

        short8 af[4], bfr[4];
#pragma unroll
        for (int i = 0; i < 4; ++i) af[i] = *(const short8*)&As[(wr * 64 + i * 16 + fr) * 32 + kg];
#pragma unroll
        for (int j = 0; j < 4; ++j) bfr[j] = *(const short8*)&Bs[(wc * 64 + j * 16 + fr) * 32 + kg];

        __syncthreads();   // frags in regs; LDS safe to overwrite

        if (kt + 1 < KDIM / 32) {
            const int ko = (kt + 1) * 32;
            gl_lds16(arow0 + ko, ldsA0); gl_lds16(arow1 + ko, ldsA1);
            gl_lds16(brow0 + ko, ldsB0); gl_lds16(brow1 + ko, ldsB1);
        }

#pragma unroll
        for (int i = 0; i < 4; ++i)
#pragma unroll
            for (int j = 0; j < 4; ++j)
                acc[i][j] = __builtin_amdgcn_mfma_f32_16x16x32_bf16(af[i], bfr[j], acc[i][j], 0, 0, 0);
    }
}

// ---------------- GEMM1: H = gelu(Xg @ W1[e]^T + b1[e]) ----------------
__global__ __launch_bounds__(256) void gemm1_k(const short* __restrict__ xb,
                                               const short* __restrict__ W1b,
                                               const float* __restrict__ b1,
                                               const int* __restrict__ cnt,
                                               const int* __restrict__ offs,
                                               const int* __restrict__ ptok,
                                               short* __restrict__ H) {
    __shared__ __align__(16) short As[128 * 32];
    __shared__ __align__(16) short Bs[128 * 32];
    const int e = blockIdx.z;
    const int cnt_e = cnt[e], offs_e = offs[e];
    const int m0 = blockIdx.y * 128;
    if (m0 >= cnt_e) return;
    const int n0 = blockIdx.x * 128;

    f32x4 acc[4][4];
    gemm_core<DIM, true>(xb, ptok, W1b + (size_t)e * FF * DIM, offs_e, cnt_e, m0, n0, acc, As, Bs);

    const int lane = threadIdx.x & 63, wave = threadIdx.x >> 6;
    const int wr = wave >> 1, wc = wave & 1;
    const int colb = lane & 15, rowb = (lane >> 4) * 4;
#pragma unroll
    for (int i = 0; i < 4; ++i) {
#pragma unroll
        for (int r = 0; r < 4; ++r) {
            const int gm = m0 + wr * 64 + i * 16 + rowb + r;
            if (gm >= cnt_e) continue;
#pragma unroll
            for (int j = 0; j < 4; ++j) {
                const int n = n0 + wc * 64 + j * 16 + colb;
                float v = acc[i][j][r] + b1[e * FF + n];
                v = 0.5f * v * (1.f + erff(v * 0.70710678118f));
                H[(size_t)(offs_e + gm) * FF + n] = bf16_of(v);
            }
        }
    }
}

// ---------------- GEMM2: out += gate * (H @ W2[e]^T + b2[e]) ----------------
__global__ __launch_bounds__(256) void gemm2_k(const short* __restrict__ H,
                                               const short* __restrict__ W2b,
                                               const float* __restrict__ b2,
                                               const int* __restrict__ cnt,
                                               const int* __restrict__ offs,
                                               const int* __restrict__ ptok,
                                               const float* __restrict__ pw,
                                               float* __restrict__ out) {
    __shared__ __align__(16) short As[128 * 32];
    __shared__ __align__(16) short Bs[128 * 32];
    const int e = blockIdx.z;
    const int cnt_e = cnt[e], offs_e = offs[e];
    const int m0 = blockIdx.y * 128;
    if (m0 >= cnt_e) return;
    const int n0 = blockIdx.x * 128;

    f32x4 acc[4][4];
    gemm_core<FF, false>(H, nullptr, W2b + (size_t)e * DIM * FF, offs_e, cnt_e, m0, n0, acc, As, Bs);

    const int lane = threadIdx.x & 63, wave = threadIdx.x >> 6;
    const int wr = wave >> 1, wc = wave & 1;
    const int colb = lane & 15, rowb = (lane >> 4) * 4;
#pragma unroll
    for (int i = 0; i < 4; ++i) {
#pragma unroll
        for (int r = 0; r < 4; ++r) {
            const int gm = m0 + wr * 64 + i * 16 + rowb + r;
            if (gm >= cnt_e) continue;
            const int tok = ptok[offs_e + gm];
            const float g = pw[offs_e + gm];
#pragma unroll
            for (int j = 0; j < 4; ++j) {
                const int n = n0 + wc * 64 + j * 16 + colb;
                float v = acc[i][j][r] + b2[e * DIM + n];
                atomicAdd(&out[(size_t)tok * DIM + n], g * v);
            }
        }
    }
}

// ---------------- launch ----------------
extern "C" void kernel_launch(void* const* d_in, const int* in_sizes, int n_in,
                              void* d_out, int out_size, void* d_ws, size_t ws_size,
                              hipStream_t stream) {
    const float* x  = (const float*)d_in[0];
    const float* Wr = (const float*)d_in[1];
    const float* W1 = (const float*)d_in[2];
    const float* b1 = (const float*)d_in[3];
    const float* W2 = (const float*)d_in[4];
    const float* b2 = (const float*)d_in[5];
    float* out = (float*)d_out;

    char* w = (char*)d_ws;
    int*   cnt   = (int*)w;                          // 32 B
    int*   offs  = (int*)(w + 64);                   // 36 B
    int*   a_exp = (int*)(w + 128);
    int*   a_pos = a_exp + NASSIGN;
    int*   ptok  = a_pos + NASSIGN;
    float* a_w   = (float*)(ptok + NASSIGN);
    float* pw    = a_w + NASSIGN;
    char*  p     = (char*)(pw + NASSIGN);
    p = (char*)(((uintptr_t)p + 255) & ~(uintptr_t)255);
    short* xb  = (short*)p;                p += (size_t)NTOK * DIM * 2;
    short* W1b = (short*)p;                p += (size_t)NE * FF * DIM * 2;
    short* W2b = (short*)p;                p += (size_t)NE * DIM * FF * 2;
    short* H   = (short*)p;                // NASSIGN * FF * 2 = 134 MB

    hipMemsetAsync(cnt, 0, 32, stream);
    hipMemsetAsync(out, 0, (size_t)NTOK * DIM * sizeof(float), stream);

    cvt_k<<<(NTOK * DIM / 8 + 255) / 256, 256, 0, stream>>>(x, xb, NTOK * DIM / 8);
    cvt_k<<<(NE * FF * DIM / 8 + 255) / 256, 256, 0, stream>>>(W1, W1b, NE * FF * DIM / 8);
    cvt_k<<<(NE * DIM * FF / 8 + 255) / 256, 256, 0, stream>>>(W2, W2b, NE * DIM * FF / 8);

    router_k<<<NTOK, 64, 0, stream>>>(x, Wr, cnt, a_exp, a_pos, a_w);
    offsets_k<<<1, 64, 0, stream>>>(cnt, offs);
    scatter_k<<<NASSIGN / 256, 256, 0, stream>>>(a_exp, a_pos, a_w, offs, ptok, pw);

    gemm1_k<<<dim3(FF / 128, NTOK / 128, NE), 256, 0, stream>>>(xb, W1b, b1, cnt, offs, ptok, H);
    gemm2_k<<<dim3(DIM / 128, NTOK / 128, NE), 256, 0, stream>>>(H, W2b, b2, cnt, offs, ptok, pw, out);
}

// Round 3
// 754.552 us; speedup vs baseline: 1.2631x; 1.1084x over previous
//
#include <hip/hip_runtime.h>
#include <hip/hip_bf16.h>
#include <math.h>
#include <stdint.h>

#define DIM 1024
#define FF 4096
#define NE 8
#define NTOK 8192
#define NASSIGN (NTOK * 2)

typedef short short8 __attribute__((ext_vector_type(8)));
typedef float f32x4 __attribute__((ext_vector_type(4)));

static __device__ __forceinline__ short bf16_of(float f) {
    union { float f; unsigned u; } v; v.f = f;
    unsigned r = v.u + 0x7fffu + ((v.u >> 16) & 1u);   // RNE
    return (short)(r >> 16);
}

static __device__ __forceinline__ short8 cvt8(float4 a, float4 b) {
    short8 r;
    r[0] = bf16_of(a.x); r[1] = bf16_of(a.y); r[2] = bf16_of(a.z); r[3] = bf16_of(a.w);
    r[4] = bf16_of(b.x); r[5] = bf16_of(b.y); r[6] = bf16_of(b.z); r[7] = bf16_of(b.w);
    return r;
}

static __device__ __forceinline__ void gl_lds16(const short* g, short* lds) {
    __builtin_amdgcn_global_load_lds(
        (const __attribute__((address_space(1))) void*)g,
        (__attribute__((address_space(3))) void*)lds, 16, 0, 0);
}

// ---------------- f32 -> bf16 bulk convert ----------------
__global__ __launch_bounds__(256) void cvt_k(const float* __restrict__ in,
                                             short* __restrict__ out, int n8) {
    int i = blockIdx.x * blockDim.x + threadIdx.x;
    if (i >= n8) return;
    float4 a = ((const float4*)in)[2 * i];
    float4 b = ((const float4*)in)[2 * i + 1];
    ((short8*)out)[i] = cvt8(a, b);
}

// ---------------- router ----------------
__global__ void router_k(const float* __restrict__ x, const float* __restrict__ Wr,
                         int* __restrict__ cnt, int* __restrict__ a_exp,
                         int* __restrict__ a_pos, float* __restrict__ a_w) {
    int t = blockIdx.x;
    int lane = threadIdx.x;
    const float* xr = x + (size_t)t * DIM;
    float p[NE];
#pragma unroll
    for (int e = 0; e < NE; ++e) p[e] = 0.f;
    for (int i = 0; i < DIM / 64; ++i) {
        float xv = xr[lane + i * 64];
#pragma unroll
        for (int e = 0; e < NE; ++e) p[e] += xv * Wr[e * DIM + lane + i * 64];
    }
#pragma unroll
    for (int off = 32; off >= 1; off >>= 1)
#pragma unroll
        for (int e = 0; e < NE; ++e) p[e] += __shfl_xor(p[e], off);
    if (lane == 0) {
        float mx = p[0];
#pragma unroll
        for (int e = 1; e < NE; ++e) mx = fmaxf(mx, p[e]);
        float pr[NE]; float s = 0.f;
#pragma unroll
        for (int e = 0; e < NE; ++e) { pr[e] = expf(p[e] - mx); s += pr[e]; }
#pragma unroll
        for (int e = 0; e < NE; ++e) pr[e] /= s;
        int i1 = 0;
#pragma unroll
        for (int e = 1; e < NE; ++e) if (pr[e] > pr[i1]) i1 = e;
        int i2 = (i1 == 0) ? 1 : 0;
#pragma unroll
        for (int e = 0; e < NE; ++e) if (e != i1 && pr[e] > pr[i2]) i2 = e;
        float w1 = pr[i1], w2 = pr[i2], nrm = w1 + w2;
        w1 /= nrm; w2 /= nrm;
        int p1 = atomicAdd(&cnt[i1], 1);
        int p2 = atomicAdd(&cnt[i2], 1);
        a_exp[2 * t] = i1;     a_pos[2 * t] = p1;     a_w[2 * t] = w1;
        a_exp[2 * t + 1] = i2; a_pos[2 * t + 1] = p2; a_w[2 * t + 1] = w2;
    }
}

__global__ void offsets_k(const int* __restrict__ cnt, int* __restrict__ offs) {
    if (threadIdx.x == 0) {
        int s = 0;
        for (int e = 0; e < NE; ++e) { offs[e] = s; s += cnt[e]; }
        offs[NE] = s;
    }
}

// also records token-slot -> sorted-row map for the combine kernel
__global__ void scatter_k(const int* __restrict__ a_exp, const int* __restrict__ a_pos,
                          const float* __restrict__ a_w, const int* __restrict__ offs,
                          int* __restrict__ ptok, float* __restrict__ pw,
                          int* __restrict__ slot_of) {
    int a = blockIdx.x * blockDim.x + threadIdx.x;
    if (a >= NASSIGN) return;
    int e = a_exp[a];
    int r = offs[e] + a_pos[a];
    ptok[r] = a >> 1;
    pw[r] = a_w[a];
    slot_of[a] = r;
}

// ---------------- grouped GEMM core (bf16, global_load_lds staging) ----------------
template <int KDIM, bool GATHER>
__device__ __forceinline__ void gemm_core(const short* __restrict__ A,
                                          const int* __restrict__ ptok,
                                          const short* __restrict__ B,
                                          int offs_e, int cnt_e, int m0, int n0,
                                          f32x4 acc[4][4],
                                          short* As, short* Bs) {
    const int tid = threadIdx.x;
    const int lane = tid & 63, wave = tid >> 6;
    const int wr = wave >> 1, wc = wave & 1;

#pragma unroll
    for (int i = 0; i < 4; ++i)
#pragma unroll
        for (int j = 0; j < 4; ++j) acc[i][j] = (f32x4){0.f, 0.f, 0.f, 0.f};

    const int ar = tid >> 2, kq = tid & 3;

    int gm0 = m0 + ar;      if (gm0 >= cnt_e) gm0 = cnt_e - 1;
    int gm1 = m0 + ar + 64; if (gm1 >= cnt_e) gm1 = cnt_e - 1;
    const short* arow0 = A + (GATHER ? (size_t)ptok[offs_e + gm0]
                                     : (size_t)(offs_e + gm0)) * KDIM + kq * 8;
    const short* arow1 = A + (GATHER ? (size_t)ptok[offs_e + gm1]
                                     : (size_t)(offs_e + gm1)) * KDIM + kq * 8;
    const short* brow0 = B + (size_t)(n0 + ar) * KDIM + kq * 8;
    const short* brow1 = B + (size_t)(n0 + ar + 64) * KDIM + kq * 8;

    short* ldsA0 = As + tid * 8;
    short* ldsA1 = As + (tid + 256) * 8;
    short* ldsB0 = Bs + tid * 8;
    short* ldsB1 = Bs + (tid + 256) * 8;

    const int fr = lane & 15, kg = (lane >> 4) * 8;

    gl_lds16(arow0, ldsA0); gl_lds16(arow1, ldsA1);
    gl_lds16(brow0, ldsB0); gl_lds16(brow1, ldsB1);

    for (int kt = 0; kt < KDIM / 32; ++kt) {
        __syncthreads();

        short8 af[4], bfr[4];
#pragma unroll
        for (int i = 0; i < 4; ++i) af[i] = *(const short8*)&As[(wr * 64 + i * 16 + fr) * 32 + kg];
#pragma unroll
        for (int j = 0; j < 4; ++j) bfr[j] = *(const short8*)&Bs[(wc * 64 + j * 16 + fr) * 32 + kg];

        __syncthreads();

        if (kt + 1 < KDIM / 32) {
            const int ko = (kt + 1) * 32;
            gl_lds16(arow0 + ko, ldsA0); gl_lds16(arow1 + ko, ldsA1);
            gl_lds16(brow0 + ko, ldsB0); gl_lds16(brow1 + ko, ldsB1);
        }

#pragma unroll
        for (int i = 0; i < 4; ++i)
#pragma unroll
            for (int j = 0; j < 4; ++j)
                acc[i][j] = __builtin_amdgcn_mfma_f32_16x16x32_bf16(af[i], bfr[j], acc[i][j], 0, 0, 0);
    }
}

// ---------------- GEMM1: H = gelu(Xg @ W1[e]^T + b1[e]), 1D grid + XCD swizzle --------
#define G1_NX (FF / 128)        // 32
#define G1_NY (NTOK / 128)      // 64
#define G1_NWG (G1_NX * G1_NY * NE)
__global__ __launch_bounds__(256) void gemm1_k(const short* __restrict__ xb,
                                               const short* __restrict__ W1b,
                                               const float* __restrict__ b1,
                                               const int* __restrict__ cnt,
                                               const int* __restrict__ offs,
                                               const int* __restrict__ ptok,
                                               short* __restrict__ H) {
    __shared__ __align__(16) short As[128 * 32];
    __shared__ __align__(16) short Bs[128 * 32];
    // bijective chunked XCD swizzle (nwg % 8 == 0): consecutive wg share an A m-tile
    int wg = (blockIdx.x % 8) * (G1_NWG / 8) + blockIdx.x / 8;
    const int n0 = (wg % G1_NX) * 128;  wg /= G1_NX;
    const int m0 = (wg % G1_NY) * 128;  wg /= G1_NY;
    const int e = wg;
    const int cnt_e = cnt[e], offs_e = offs[e];
    if (m0 >= cnt_e) return;

    f32x4 acc[4][4];
    gemm_core<DIM, true>(xb, ptok, W1b + (size_t)e * FF * DIM, offs_e, cnt_e, m0, n0, acc, As, Bs);

    const int lane = threadIdx.x & 63, wave = threadIdx.x >> 6;
    const int wr = wave >> 1, wc = wave & 1;
    const int colb = lane & 15, rowb = (lane >> 4) * 4;
#pragma unroll
    for (int i = 0; i < 4; ++i) {
#pragma unroll
        for (int r = 0; r < 4; ++r) {
            const int gm = m0 + wr * 64 + i * 16 + rowb + r;
            if (gm >= cnt_e) continue;
#pragma unroll
            for (int j = 0; j < 4; ++j) {
                const int n = n0 + wc * 64 + j * 16 + colb;
                float v = acc[i][j][r] + b1[e * FF + n];
                v = 0.5f * v * (1.f + erff(v * 0.70710678118f));
                H[(size_t)(offs_e + gm) * FF + n] = bf16_of(v);
            }
        }
    }
}

// ---------------- GEMM2: y[slot] = H @ W2[e]^T + b2[e]  (no atomics) ----------------
#define G2_NX (DIM / 128)       // 8
#define G2_NY (NTOK / 128)      // 64
#define G2_NWG (G2_NX * G2_NY * NE)
__global__ __launch_bounds__(256) void gemm2_k(const short* __restrict__ H,
                                               const short* __restrict__ W2b,
                                               const float* __restrict__ b2,
                                               const int* __restrict__ cnt,
                                               const int* __restrict__ offs,
                                               float* __restrict__ y) {
    __shared__ __align__(16) short As[128 * 32];
    __shared__ __align__(16) short Bs[128 * 32];
    int wg = (blockIdx.x % 8) * (G2_NWG / 8) + blockIdx.x / 8;
    const int n0 = (wg % G2_NX) * 128;  wg /= G2_NX;
    const int m0 = (wg % G2_NY) * 128;  wg /= G2_NY;
    const int e = wg;
    const int cnt_e = cnt[e], offs_e = offs[e];
    if (m0 >= cnt_e) return;

    f32x4 acc[4][4];
    gemm_core<FF, false>(H, nullptr, W2b + (size_t)e * DIM * FF, offs_e, cnt_e, m0, n0, acc, As, Bs);

    const int lane = threadIdx.x & 63, wave = threadIdx.x >> 6;
    const int wr = wave >> 1, wc = wave & 1;
    const int colb = lane & 15, rowb = (lane >> 4) * 4;
#pragma unroll
    for (int i = 0; i < 4; ++i) {
#pragma unroll
        for (int r = 0; r < 4; ++r) {
            const int gm = m0 + wr * 64 + i * 16 + rowb + r;
            if (gm >= cnt_e) continue;
#pragma unroll
            for (int j = 0; j < 4; ++j) {
                const int n = n0 + wc * 64 + j * 16 + colb;
                y[(size_t)(offs_e + gm) * DIM + n] = acc[i][j][r] + b2[e * DIM + n];
            }
        }
    }
}

// ---------------- combine: out[t] = w1*y[s1] + w2*y[s2] ----------------
__global__ __launch_bounds__(256) void combine_k(const float* __restrict__ y,
                                                 const int* __restrict__ slot_of,
                                                 const float* __restrict__ a_w,
                                                 float* __restrict__ out) {
    const int t = blockIdx.x;
    const int c = threadIdx.x;          // 256 threads * float4 = 1024 cols
    const int s1 = slot_of[2 * t], s2 = slot_of[2 * t + 1];
    const float w1 = a_w[2 * t], w2 = a_w[2 * t + 1];
    float4 v1 = ((const float4*)(y + (size_t)s1 * DIM))[c];
    float4 v2 = ((const float4*)(y + (size_t)s2 * DIM))[c];
    float4 o;
    o.x = w1 * v1.x + w2 * v2.x;
    o.y = w1 * v1.y + w2 * v2.y;
    o.z = w1 * v1.z + w2 * v2.z;
    o.w = w1 * v1.w + w2 * v2.w;
    ((float4*)(out + (size_t)t * DIM))[c] = o;
}

// ---------------- launch ----------------
extern "C" void kernel_launch(void* const* d_in, const int* in_sizes, int n_in,
                              void* d_out, int out_size, void* d_ws, size_t ws_size,
                              hipStream_t stream) {
    const float* x  = (const float*)d_in[0];
    const float* Wr = (const float*)d_in[1];
    const float* W1 = (const float*)d_in[2];
    const float* b1 = (const float*)d_in[3];
    const float* W2 = (const float*)d_in[4];
    const float* b2 = (const float*)d_in[5];
    float* out = (float*)d_out;

    char* w = (char*)d_ws;
    int*   cnt     = (int*)w;                          // 32 B
    int*   offs    = (int*)(w + 64);                   // 36 B
    int*   a_exp   = (int*)(w + 128);
    int*   a_pos   = a_exp + NASSIGN;
    int*   ptok    = a_pos + NASSIGN;
    int*   slot_of = ptok + NASSIGN;
    float* a_w     = (float*)(slot_of + NASSIGN);
    float* pw      = a_w + NASSIGN;
    char*  p       = (char*)(pw + NASSIGN);
    p = (char*)(((uintptr_t)p + 255) & ~(uintptr_t)255);
    short* xb  = (short*)p;                p += (size_t)NTOK * DIM * 2;
    short* W1b = (short*)p;                p += (size_t)NE * FF * DIM * 2;
    short* W2b = (short*)p;                p += (size_t)NE * DIM * FF * 2;
    short* H   = (short*)p;                // NASSIGN * FF * 2 = 134 MB
    // y aliases W1b: dead after gemm1; NASSIGN*DIM*4 == NE*FF*DIM*2 == 67 MB
    float* y   = (float*)W1b;

    hipMemsetAsync(cnt, 0, 32, stream);

    cvt_k<<<(NTOK * DIM / 8 + 255) / 256, 256, 0, stream>>>(x, xb, NTOK * DIM / 8);
    cvt_k<<<(NE * FF * DIM / 8 + 255) / 256, 256, 0, stream>>>(W1, W1b, NE * FF * DIM / 8);
    cvt_k<<<(NE * DIM * FF / 8 + 255) / 256, 256, 0, stream>>>(W2, W2b, NE * DIM * FF / 8);

    router_k<<<NTOK, 64, 0, stream>>>(x, Wr, cnt, a_exp, a_pos, a_w);
    offsets_k<<<1, 64, 0, stream>>>(cnt, offs);
    scatter_k<<<NASSIGN / 256, 256, 0, stream>>>(a_exp, a_pos, a_w, offs, ptok, pw, slot_of);

    gemm1_k<<<G1_NWG, 256, 0, stream>>>(xb, W1b, b1, cnt, offs, ptok, H);
    gemm2_k<<<G2_NWG, 256, 0, stream>>>(H, W2b, b2, cnt, offs, y);
    combine_k<<<NTOK, 256, 0, stream>>>(y, slot_of, a_w, out);
}